// Round 7
// baseline (302.803 us; speedup 1.0000x reference)
//
#include <hip/hip_runtime.h>

#define MDIM 32768
#define NDIM 4096
#define KDIM 1024

typedef __attribute__((ext_vector_type(4))) float floatx4;
typedef __attribute__((ext_vector_type(16))) float float16v;
typedef __attribute__((ext_vector_type(4))) int int4v;
typedef __attribute__((ext_vector_type(8))) int int8v;

// ---- quantize x: f32 [M,K] -> fp8 e4m3 bytes [M,K] (RNE, saturating) ----
__global__ __launch_bounds__(256) void quant_x_kernel(
    const float* __restrict__ x, char* __restrict__ out, int n16) {
    int idx = blockIdx.x * blockDim.x + threadIdx.x;
    int stride = gridDim.x * blockDim.x;
    const floatx4* xv = (const floatx4*)x;
    int4v* ov = (int4v*)out;
    for (int i = idx; i < n16; i += stride) {
        int4v o;
#pragma unroll
        for (int j = 0; j < 4; ++j) {
            floatx4 v = __builtin_nontemporal_load(&xv[i * 4 + j]);  // x never reused
            int pk = __builtin_amdgcn_cvt_pk_fp8_f32(v.x, v.y, 0, false);
            pk = __builtin_amdgcn_cvt_pk_fp8_f32(v.z, v.w, pk, true);
            o[j] = pk;
        }
        ov[i] = o;
    }
}

// ---- quantize + transpose w: f32 [K,N] -> fp8 e4m3 [N,K] ----
__global__ __launch_bounds__(256) void quant_w_kernel(
    const float* __restrict__ w, char* __restrict__ wT) {
    __shared__ char tile[64][68];
    int nbase = blockIdx.x * 64;
    int kbase = blockIdx.y * 64;
    int t = threadIdx.x;
#pragma unroll
    for (int i = 0; i < 4; ++i) {
        int fidx = t + i * 256;      // 1024 float4s per 64x64 tile
        int r = fidx >> 4;           // k row 0..63
        int c4 = fidx & 15;          // float4 col
        floatx4 v = *(const floatx4*)&w[(long)(kbase + r) * NDIM + nbase + c4 * 4];
        int pk = __builtin_amdgcn_cvt_pk_fp8_f32(v.x, v.y, 0, false);
        pk = __builtin_amdgcn_cvt_pk_fp8_f32(v.z, v.w, pk, true);
        *(int*)&tile[r][c4 * 4] = pk;
    }
    __syncthreads();
    int n = t >> 2, kq = (t & 3) * 16;
    int outw[4];
#pragma unroll
    for (int g = 0; g < 4; ++g) {
        int v = 0;
#pragma unroll
        for (int j = 0; j < 4; ++j)
            v |= ((int)(unsigned char)tile[kq + g * 4 + j][n]) << (8 * j);
        outw[g] = v;
    }
    *(int4v*)&wT[(long)(nbase + n) * KDIM + kbase + kq] = *(int4v*)outw;
}

// ======== GEMM: MX-fp8 (unit scales). A fp8 [M,K], BT fp8 [N,K], C f32 [M,N].
// 256x256 tile, BK=128 bytes, 8 K-tiles. A staged via global_load_lds into
// 2 x 32 KB LDS bufs (XOR swizzle chunk ^= row&7, zero conflicts, verified
// r1-r6). B is NOT staged: each wave loads its B fragments directly from
// global into registers (B is 4 MB, L1/L2-resident; bm-major order keeps the
// bn panel hot). Per tile: B-loads(8 dwordx4) -> STAGE-A next(4 GL) ->
// vmcnt(12) [= exactly A(t) done; B + A(t+1) stay in flight] -> barrier ->
// 16 MFMA (A frags from LDS, B from regs) -> barrier. vmcnt never drained
// mid-loop. bm-major XCD swizzle + non-temporal C stores (round-6 wins).

#define GL(gp, lp)                                                 \
    __builtin_amdgcn_global_load_lds(                              \
        (const __attribute__((address_space(1))) void*)(gp),       \
        (__attribute__((address_space(3))) void*)(lp), 16, 0, 0)

#define VMCNT(n) asm volatile("s_waitcnt vmcnt(" #n ")" ::: "memory")
#define BARS()  { __builtin_amdgcn_s_barrier(); __builtin_amdgcn_sched_barrier(0); }

#define MFMA_SC(a_, b_, c_)                                               \
    __builtin_amdgcn_mfma_scale_f32_32x32x64_f8f6f4(                      \
        (a_), (b_), (c_), 0, 0, 0, 0x7F7F7F7F, 0, 0x7F7F7F7F)

__global__ __launch_bounds__(512) void gemm_kernel(
    const char* __restrict__ A, const char* __restrict__ BT,
    const float* __restrict__ bias, float* __restrict__ C) {
    __shared__ char lds[65536];   // A only: buf d at d*32768

    const int T = threadIdx.x;
    const int lane = T & 63;
    const int w = T >> 6;            // wave 0..7
    const int wr = w >> 2;           // 0..1 (M)
    const int wc = w & 3;            // 0..3 (N)

    // XCD-aware bijective swizzle (2048 blocks % 8 == 0), bm-MAJOR within
    // each XCD chunk: 16 consecutive blocks share one A panel (L2-resident).
    const int sw = (blockIdx.x & 7) * 256 + (blockIdx.x >> 3);
    const int bm = (sw >> 4) * 256;      // 128 M-blocks (major)
    const int bn = (sw & 15) * 256;      // 16 N-blocks (minor)

    // ---- A staging (per-thread): LDS phys chunk (T&7) of slab-row (T>>3)
    // holds logical chunk (T&7)^((T>>3)&7) (both-sides XOR involution).
    const int cs = (T & 7) ^ ((T >> 3) & 7);
    const long aOff = (long)(bm + (T >> 3)) * KDIM + cs * 16;
    const int dstB = (T >> 3) * 128 + (T & 7) * 16;

#define STAGEA(d_, t_) {                                                      \
        char* la_ = lds + (d_) * 32768 + dstB;                                \
        const char* ga_ = A + aOff + (t_) * 128;                              \
        GL(ga_, la_);                      GL(ga_ + 64 * KDIM, la_ + 8192);   \
        GL(ga_ + 128 * KDIM, la_ + 16384); GL(ga_ + 192 * KDIM, la_ + 24576); \
    }

    // ---- read-side addresses ----
    const int l31 = lane & 31;
    const int kh = lane >> 5;                 // k half-wave
    const int swz = (l31 & 7) << 4;           // row&7 == l31&7 for all frag rows
    const char* Abase = lds + (wr * 128 + l31) * 128;
    // B direct: frag (n, kk) -> row bn + wc*64 + n*32 + l31, col t*128 + kk*64 + kh*32
    const char* Bptr = BT + (long)(bn + wc * 64 + l31) * KDIM + kh * 32;

    float16v acc[4][2] = {};

#define LD32(dst_, base_, col0_) {                                        \
        int4v lo_ = *(const int4v*)((base_) + (((col0_) + 0) ^ swz));     \
        int4v hi_ = *(const int4v*)((base_) + (((col0_) + 16) ^ swz));    \
        dst_[0] = lo_[0]; dst_[1] = lo_[1]; dst_[2] = lo_[2]; dst_[3] = lo_[3]; \
        dst_[4] = hi_[0]; dst_[5] = hi_[1]; dst_[6] = hi_[2]; dst_[7] = hi_[3]; \
    }

    // Tile body: B-loads first (oldest), then next-tile A stage (youngest),
    // counted wait for A(t), barrier, compute.
#define TILE(d_, t_, stage_, vm_) {                                       \
        const char* bp_ = Bptr + (t_) * 128;                              \
        int8v b00 = *(const int8v*)(bp_);                                 \
        int8v b01 = *(const int8v*)(bp_ + 32 * KDIM);                     \
        int8v b10 = *(const int8v*)(bp_ + 64);                            \
        int8v b11 = *(const int8v*)(bp_ + 64 + 32 * KDIM);                \
        stage_;                                                           \
        vm_;                                                              \
        BARS();                                                           \
        const char* ap_ = Abase + (d_) * 32768;                           \
        int8v a0, a1, a2, a3;                                             \
        LD32(a0, ap_, kh * 32);          LD32(a1, ap_ + 4096, kh * 32);   \
        LD32(a2, ap_ + 8192, kh * 32);   LD32(a3, ap_ + 12288, kh * 32);  \
        __builtin_amdgcn_s_setprio(1);                                    \
        acc[0][0] = MFMA_SC(a0, b00, acc[0][0]);                          \
        acc[0][1] = MFMA_SC(a0, b01, acc[0][1]);                          \
        acc[1][0] = MFMA_SC(a1, b00, acc[1][0]);                          \
        acc[1][1] = MFMA_SC(a1, b01, acc[1][1]);                          \
        acc[2][0] = MFMA_SC(a2, b00, acc[2][0]);                          \
        acc[2][1] = MFMA_SC(a2, b01, acc[2][1]);                          \
        acc[3][0] = MFMA_SC(a3, b00, acc[3][0]);                          \
        acc[3][1] = MFMA_SC(a3, b01, acc[3][1]);                          \
        __builtin_amdgcn_s_setprio(0);                                    \
        LD32(a0, ap_, 64 + kh * 32);        LD32(a1, ap_ + 4096, 64 + kh * 32); \
        LD32(a2, ap_ + 8192, 64 + kh * 32); LD32(a3, ap_ + 12288, 64 + kh * 32); \
        __builtin_amdgcn_s_setprio(1);                                    \
        acc[0][0] = MFMA_SC(a0, b10, acc[0][0]);                          \
        acc[0][1] = MFMA_SC(a0, b11, acc[0][1]);                          \
        acc[1][0] = MFMA_SC(a1, b10, acc[1][0]);                          \
        acc[1][1] = MFMA_SC(a1, b11, acc[1][1]);                          \
        acc[2][0] = MFMA_SC(a2, b10, acc[2][0]);                          \
        acc[2][1] = MFMA_SC(a2, b11, acc[2][1]);                          \
        acc[3][0] = MFMA_SC(a3, b10, acc[3][0]);                          \
        acc[3][1] = MFMA_SC(a3, b11, acc[3][1]);                          \
        __builtin_amdgcn_s_setprio(0);                                    \
        BARS();                                                           \
    }

    // ---- pipeline: 8 K-tiles, 2 A-bufs. Steady state entering tile t:
    // 4 outstanding (A(t)). +B(t)=8 -> 12; +A(t+1)=4 -> 16; vmcnt(12) = A(t)
    // done, B(t)+A(t+1) in flight. Last tile: 4+8=12, vmcnt(8) = A(7) done.
    STAGEA(0, 0);
    TILE(0, 0, STAGEA(1, 1), VMCNT(12));
    TILE(1, 1, STAGEA(0, 2), VMCNT(12));
    TILE(0, 2, STAGEA(1, 3), VMCNT(12));
    TILE(1, 3, STAGEA(0, 4), VMCNT(12));
    TILE(0, 4, STAGEA(1, 5), VMCNT(12));
    TILE(1, 5, STAGEA(0, 6), VMCNT(12));
    TILE(0, 6, STAGEA(1, 7), VMCNT(12));
    TILE(1, 7, (void)0,      VMCNT(8));

    // ---- C write + bias (non-temporal: C is write-once, keep L2/L3 for A/B).
    // 32x32 C/D frag: col=lane&31, row=(r&3)+8*(r>>2)+4*kh.
#pragma unroll
    for (int n = 0; n < 2; ++n) {
        int gcol = bn + wc * 64 + n * 32 + l31;
        float bv = bias[gcol];
#pragma unroll
        for (int m = 0; m < 4; ++m) {
            long rbase = bm + wr * 128 + m * 32 + 4 * kh;
#pragma unroll
            for (int r = 0; r < 16; ++r) {
                long grow = rbase + (r & 3) + 8 * (r >> 2);
                __builtin_nontemporal_store(acc[m][n][r] + bv, &C[grow * NDIM + gcol]);
            }
        }
    }
#undef STAGEA
#undef TILE
#undef LD32
}

extern "C" void kernel_launch(void* const* d_in, const int* in_sizes, int n_in,
                              void* d_out, int out_size, void* d_ws, size_t ws_size,
                              hipStream_t stream) {
    (void)in_sizes; (void)n_in; (void)out_size; (void)ws_size;
    const float* x = (const float*)d_in[0];
    const float* wk = (const float*)d_in[1];
    const float* bias = (const float*)d_in[2];
    float* out = (float*)d_out;

    char* xq = (char*)d_ws;                                       // 32 MB
    char* wT = (char*)d_ws + (size_t)MDIM * KDIM;                 // 4 MB

    quant_x_kernel<<<2048, 256, 0, stream>>>(x, xq, MDIM * KDIM / 16);
    quant_w_kernel<<<dim3(NDIM / 64, KDIM / 64), 256, 0, stream>>>(wk, wT);
    gemm_kernel<<<2048, 512, 0, stream>>>(xq, wT, bias, out);
}

// Round 8
// 229.260 us; speedup vs baseline: 1.3208x; 1.3208x over previous
//
#include <hip/hip_runtime.h>

#define MDIM 32768
#define NDIM 4096
#define KDIM 1024

typedef __attribute__((ext_vector_type(4))) float floatx4;
typedef __attribute__((ext_vector_type(16))) float float16v;
typedef __attribute__((ext_vector_type(4))) int int4v;
typedef __attribute__((ext_vector_type(8))) int int8v;

// ---- quantize x: f32 [M,K] -> fp8 e4m3 bytes [M,K] (RNE, saturating) ----
__global__ __launch_bounds__(256) void quant_x_kernel(
    const float* __restrict__ x, char* __restrict__ out, int n16) {
    int idx = blockIdx.x * blockDim.x + threadIdx.x;
    int stride = gridDim.x * blockDim.x;
    const floatx4* xv = (const floatx4*)x;
    int4v* ov = (int4v*)out;
    for (int i = idx; i < n16; i += stride) {
        int4v o;
#pragma unroll
        for (int j = 0; j < 4; ++j) {
            floatx4 v = __builtin_nontemporal_load(&xv[i * 4 + j]);  // x never reused
            int pk = __builtin_amdgcn_cvt_pk_fp8_f32(v.x, v.y, 0, false);
            pk = __builtin_amdgcn_cvt_pk_fp8_f32(v.z, v.w, pk, true);
            o[j] = pk;
        }
        ov[i] = o;
    }
}

// ---- quantize + transpose w: f32 [K,N] -> fp8 e4m3, FRAG-LINEAR layout ----
// Fragment (n0, k0) = B rows n0*32..+31, k bytes k0*64..+63, stored contiguous
// 2 KB at (n0*16 + k0)*2048; within: byte = (n&31)*64 + (k&63). A wave's MFMA
// B-operand load is then a contiguous 2 KB region (perfectly coalescable).
__global__ __launch_bounds__(256) void quant_w_kernel(
    const float* __restrict__ w, char* __restrict__ wT) {
    __shared__ char tile[64][68];
    int nbase = blockIdx.x * 64;
    int kbase = blockIdx.y * 64;
    int t = threadIdx.x;
#pragma unroll
    for (int i = 0; i < 4; ++i) {
        int fidx = t + i * 256;      // 1024 float4s per 64x64 tile
        int r = fidx >> 4;           // k row 0..63
        int c4 = fidx & 15;          // float4 col
        floatx4 v = *(const floatx4*)&w[(long)(kbase + r) * NDIM + nbase + c4 * 4];
        int pk = __builtin_amdgcn_cvt_pk_fp8_f32(v.x, v.y, 0, false);
        pk = __builtin_amdgcn_cvt_pk_fp8_f32(v.z, v.w, pk, true);
        *(int*)&tile[r][c4 * 4] = pk;
    }
    __syncthreads();
    int n = t >> 2, kq = (t & 3) * 16;
    int outw[4];
#pragma unroll
    for (int g = 0; g < 4; ++g) {
        int v = 0;
#pragma unroll
        for (int j = 0; j < 4; ++j)
            v |= ((int)(unsigned char)tile[kq + g * 4 + j][n]) << (8 * j);
        outw[g] = v;
    }
    int n0 = blockIdx.x * 2 + (n >> 5);   // abs N / 32
    int k0 = blockIdx.y;                  // abs K / 64
    long addr = (long)(n0 * 16 + k0) * 2048 + (n & 31) * 64 + kq;
    *(int4v*)&wT[addr] = *(int4v*)outw;
}

// ======== GEMM: MX-fp8 (unit scales). A fp8 [M,K], B frag-linear, C f32 [M,N].
// 256x256 tile, BK=128, 8 K-tiles. A staged via global_load_lds into 3 x 32 KB
// LDS bufs (XOR swizzle chunk ^= row&7; zero conflicts, verified r1-r6),
// 2-tile lead, ONE barrier per tile (stage lands post-barrier into buf
// (t+2)%3; the tile-top barrier orders it vs readers from 2 tiles ago).
// B read straight to registers from the frag-linear buffer (L1/L2-resident;
// contiguous per-fragment). vmcnt counted: VMCNT(12) drains exactly A(t);
// compiler's B-waits bottom at vmcnt(4), keeping the A-lead in flight.
// bm-major XCD swizzle + non-temporal C stores (round-6 wins).

#define GL(gp, lp)                                                 \
    __builtin_amdgcn_global_load_lds(                              \
        (const __attribute__((address_space(1))) void*)(gp),       \
        (__attribute__((address_space(3))) void*)(lp), 16, 0, 0)

#define VMCNT(n) asm volatile("s_waitcnt vmcnt(" #n ")" ::: "memory")
#define BARS()  { __builtin_amdgcn_s_barrier(); __builtin_amdgcn_sched_barrier(0); }

#define MFMA_SC(a_, b_, c_)                                               \
    __builtin_amdgcn_mfma_scale_f32_32x32x64_f8f6f4(                      \
        (a_), (b_), (c_), 0, 0, 0, 0x7F7F7F7F, 0, 0x7F7F7F7F)

__global__ __launch_bounds__(512) void gemm_kernel(
    const char* __restrict__ A, const char* __restrict__ BT,
    const float* __restrict__ bias, float* __restrict__ C) {
    __shared__ char lds[98304];   // 3 A-bufs, buf d at d*32768

    const int T = threadIdx.x;
    const int lane = T & 63;
    const int w = T >> 6;            // wave 0..7
    const int wr = w >> 2;           // 0..1 (M)
    const int wc = w & 3;            // 0..3 (N)

    // XCD-aware bijective swizzle (2048 blocks % 8 == 0), bm-MAJOR within
    // each XCD chunk: 16 consecutive blocks share one A panel (L2-resident).
    const int sw = (blockIdx.x & 7) * 256 + (blockIdx.x >> 3);
    const int bm = (sw >> 4) * 256;      // 128 M-blocks (major)
    const int bn = (sw & 15) * 256;      // 16 N-blocks (minor)

    // ---- A staging: LDS phys chunk (T&7) of slab-row (T>>3) holds logical
    // chunk (T&7)^((T>>3)&7) (both-sides XOR involution).
    const int cs = (T & 7) ^ ((T >> 3) & 7);
    const long aOff = (long)(bm + (T >> 3)) * KDIM + cs * 16;
    const int dstB = (T >> 3) * 128 + (T & 7) * 16;

#define STAGEA(d_, t_) {                                                      \
        char* la_ = lds + (d_) * 32768 + dstB;                                \
        const char* ga_ = A + aOff + (t_) * 128;                              \
        GL(ga_, la_);                      GL(ga_ + 64 * KDIM, la_ + 8192);   \
        GL(ga_ + 128 * KDIM, la_ + 16384); GL(ga_ + 192 * KDIM, la_ + 24576); \
    }

    // ---- read-side addresses ----
    const int l31 = lane & 31;
    const int kh = lane >> 5;                 // k half-wave
    const int swz = (l31 & 7) << 4;           // row&7 == l31&7 for all frag rows
    const char* Abase = lds + (wr * 128 + l31) * 128;
    // B frag-linear: frag (n0 = bn/32 + wc*2 + n, k0 = t*2 + kk) at
    // (n0*16+k0)*2048; lane byte = l31*64 + kh*32. n -> +32768, kk -> +2048,
    // t -> +4096.
    const char* Bq = BT + (long)(((bn >> 5) + wc * 2) * 16) * 2048
                   + l31 * 64 + kh * 32;

    float16v acc[4][2] = {};

#define LD32(dst_, base_, col0_) {                                        \
        int4v lo_ = *(const int4v*)((base_) + (((col0_) + 0) ^ swz));     \
        int4v hi_ = *(const int4v*)((base_) + (((col0_) + 16) ^ swz));    \
        dst_[0] = lo_[0]; dst_[1] = lo_[1]; dst_[2] = lo_[2]; dst_[3] = lo_[3]; \
        dst_[4] = hi_[0]; dst_[5] = hi_[1]; dst_[6] = hi_[2]; dst_[7] = hi_[3]; \
    }

    // Tile body: B(t) reg-loads (coalesced, L1/L2) -> counted wait for A(t)
    // -> single barrier -> stage A(t+2) -> 16 MFMA from LDS-A x reg-B.
#define TILE(c_, t_, stage_, vm_) {                                       \
        const char* bq_ = Bq + (t_) * 4096;                               \
        int8v b00 = *(const int8v*)(bq_);                                 \
        int8v b01 = *(const int8v*)(bq_ + 32768);                         \
        int8v b10 = *(const int8v*)(bq_ + 2048);                          \
        int8v b11 = *(const int8v*)(bq_ + 32768 + 2048);                  \
        vm_;                                                              \
        BARS();                                                           \
        stage_;                                                           \
        const char* ap_ = Abase + (c_) * 32768;                           \
        int8v a0, a1, a2, a3;                                             \
        LD32(a0, ap_, kh * 32);          LD32(a1, ap_ + 4096, kh * 32);   \
        LD32(a2, ap_ + 8192, kh * 32);   LD32(a3, ap_ + 12288, kh * 32);  \
        __builtin_amdgcn_s_setprio(1);                                    \
        acc[0][0] = MFMA_SC(a0, b00, acc[0][0]);                          \
        acc[0][1] = MFMA_SC(a0, b01, acc[0][1]);                          \
        acc[1][0] = MFMA_SC(a1, b00, acc[1][0]);                          \
        acc[1][1] = MFMA_SC(a1, b01, acc[1][1]);                          \
        acc[2][0] = MFMA_SC(a2, b00, acc[2][0]);                          \
        acc[2][1] = MFMA_SC(a2, b01, acc[2][1]);                          \
        acc[3][0] = MFMA_SC(a3, b00, acc[3][0]);                          \
        acc[3][1] = MFMA_SC(a3, b01, acc[3][1]);                          \
        __builtin_amdgcn_s_setprio(0);                                    \
        LD32(a0, ap_, 64 + kh * 32);        LD32(a1, ap_ + 4096, 64 + kh * 32); \
        LD32(a2, ap_ + 8192, 64 + kh * 32); LD32(a3, ap_ + 12288, 64 + kh * 32); \
        __builtin_amdgcn_s_setprio(1);                                    \
        acc[0][0] = MFMA_SC(a0, b10, acc[0][0]);                          \
        acc[0][1] = MFMA_SC(a0, b11, acc[0][1]);                          \
        acc[1][0] = MFMA_SC(a1, b10, acc[1][0]);                          \
        acc[1][1] = MFMA_SC(a1, b11, acc[1][1]);                          \
        acc[2][0] = MFMA_SC(a2, b10, acc[2][0]);                          \
        acc[2][1] = MFMA_SC(a2, b11, acc[2][1]);                          \
        acc[3][0] = MFMA_SC(a3, b10, acc[3][0]);                          \
        acc[3][1] = MFMA_SC(a3, b11, acc[3][1]);                          \
        __builtin_amdgcn_s_setprio(0);                                    \
    }

    // ---- pipeline: 8 K-tiles, 3 A-bufs, 2-tile lead, 1 barrier/tile.
    // Entering tile t: A(t)+A(t+1) = 8 outstanding; +B(t) 8 = 16;
    // VMCNT(12) drains exactly A(t). Compute's B-waits floor at vmcnt(4).
    STAGEA(0, 0); STAGEA(1, 1);
    TILE(0, 0, STAGEA(2, 2), VMCNT(12));
    TILE(1, 1, STAGEA(0, 3), VMCNT(12));
    TILE(2, 2, STAGEA(1, 4), VMCNT(12));
    TILE(0, 3, STAGEA(2, 5), VMCNT(12));
    TILE(1, 4, STAGEA(0, 6), VMCNT(12));
    TILE(2, 5, STAGEA(1, 7), VMCNT(12));
    TILE(0, 6, (void)0,      VMCNT(12));
    TILE(1, 7, (void)0,      VMCNT(8));

    // ---- C write + bias (non-temporal). 32x32 C/D frag:
    // col=lane&31, row=(r&3)+8*(r>>2)+4*kh.
#pragma unroll
    for (int n = 0; n < 2; ++n) {
        int gcol = bn + wc * 64 + n * 32 + l31;
        float bv = bias[gcol];
#pragma unroll
        for (int m = 0; m < 4; ++m) {
            long rbase = bm + wr * 128 + m * 32 + 4 * kh;
#pragma unroll
            for (int r = 0; r < 16; ++r) {
                long grow = rbase + (r & 3) + 8 * (r >> 2);
                __builtin_nontemporal_store(acc[m][n][r] + bv, &C[grow * NDIM + gcol]);
            }
        }
    }
#undef STAGEA
#undef TILE
#undef LD32
}

extern "C" void kernel_launch(void* const* d_in, const int* in_sizes, int n_in,
                              void* d_out, int out_size, void* d_ws, size_t ws_size,
                              hipStream_t stream) {
    (void)in_sizes; (void)n_in; (void)out_size; (void)ws_size;
    const float* x = (const float*)d_in[0];
    const float* wk = (const float*)d_in[1];
    const float* bias = (const float*)d_in[2];
    float* out = (float*)d_out;

    char* xq = (char*)d_ws;                                       // 32 MB
    char* wT = (char*)d_ws + (size_t)MDIM * KDIM;                 // 4 MB (frag-linear)

    quant_x_kernel<<<2048, 256, 0, stream>>>(x, xq, MDIM * KDIM / 16);
    quant_w_kernel<<<dim3(NDIM / 64, KDIM / 64), 256, 0, stream>>>(wk, wT);
    gemm_kernel<<<2048, 512, 0, stream>>>(xq, wT, bias, out);
}